// Round 4
// baseline (543.599 us; speedup 1.0000x reference)
//
#include <hip/hip_runtime.h>
#include <hip/hip_fp16.h>

#define EPSC  1e-4f
#define THETA 0.04f
#define CH    4096    // phase-1 edges per chunk
#define XEB   1024    // expand edges per block

// ws layout:
//   float[0..7]  softmax(w),  float[8..39] m,  float[40] b
//   byte 256:    int ctr[8]           (phase-1 work counters)
//   byte 4096:   slices: 8 heads x N x 16 halves (32 B per node per head)
//   after:       partial: 8 planes x EP floats

__device__ __forceinline__ void write_params(const float* w, const float* r_dist,
                                             const float* b, float* ws) {
    float wm = w[0];
    #pragma unroll
    for (int i = 1; i < 8; ++i) wm = fmaxf(wm, w[i]);
    float e[8]; float s = 0.f;
    #pragma unroll
    for (int i = 0; i < 8; ++i) { e[i] = __expf(w[i] - wm); s += e[i]; }
    float inv = 1.0f / s;
    #pragma unroll
    for (int i = 0; i < 8; ++i) ws[i] = e[i] * inv;
    float acc = 0.f;
    for (int c = 0; c < 32; ++c) {
        acc += fabsf(r_dist[c] + EPSC) + EPSC;
        ws[8 + c] = fmaxf(acc, 0.f);
    }
    ws[40] = b[0];
}

__global__ void param_kernel(const float* __restrict__ w,
                             const float* __restrict__ r_dist,
                             const float* __restrict__ b,
                             float* __restrict__ ws) {
    if (blockIdx.x == 0 && threadIdx.x == 0) write_params(w, r_dist, b, ws);
}

// build fp16 head-slices + params + zero counters
__global__ __launch_bounds__(256) void convert_kernel(
    const float* __restrict__ h,
    const float* __restrict__ w,
    const float* __restrict__ r_dist,
    const float* __restrict__ b,
    float* __restrict__ ws,
    unsigned* __restrict__ slices,   // uint view, 8 uints per (head,node)
    int* __restrict__ ctr,
    int N) {
    const long long t = (long long)blockIdx.x * 256 + threadIdx.x;
    if (t == 0) write_params(w, r_dist, b, ws);
    if (t < 8) ctr[t] = 0;
    const long long NC = (long long)N * 8;
    if (t < NC) {
        const int n = (int)(t >> 3), c = (int)(t & 7);
        const float4* p = (const float4*)(h + (size_t)n * 128 + c * 16);
        float4 v0 = p[0], v1 = p[1], v2 = p[2], v3 = p[3];
        unsigned o[8];
        __half2 x;
        x = __floats2half2_rn(v0.x, v0.y); o[0] = *(unsigned*)&x;
        x = __floats2half2_rn(v0.z, v0.w); o[1] = *(unsigned*)&x;
        x = __floats2half2_rn(v1.x, v1.y); o[2] = *(unsigned*)&x;
        x = __floats2half2_rn(v1.z, v1.w); o[3] = *(unsigned*)&x;
        x = __floats2half2_rn(v2.x, v2.y); o[4] = *(unsigned*)&x;
        x = __floats2half2_rn(v2.z, v2.w); o[5] = *(unsigned*)&x;
        x = __floats2half2_rn(v3.x, v3.y); o[6] = *(unsigned*)&x;
        x = __floats2half2_rn(v3.z, v3.w); o[7] = *(unsigned*)&x;
        unsigned* dp = slices + ((size_t)c * N + n) * 8;
        *(uint4*)(dp)     = make_uint4(o[0], o[1], o[2], o[3]);
        *(uint4*)(dp + 4) = make_uint4(o[4], o[5], o[6], o[7]);
    }
}

// phase 1: per-XCD head-class partial distances (slice stays L2-resident)
__global__ __launch_bounds__(256) void phase1_kernel(
    const unsigned* __restrict__ slices,
    const int* __restrict__ src,
    const int* __restrict__ dst,
    const float* __restrict__ wsf,
    float* __restrict__ partial,
    int* __restrict__ ctr,
    int E, int N, long long EP, int nchunk) {
    __shared__ int s_src[CH];
    __shared__ int s_dst[CH];
    __shared__ int s_chunk;

    int xcc;
    asm volatile("s_getreg_b32 %0, hwreg(HW_REG_XCC_ID)" : "=s"(xcc));
    xcc &= 7;
    const int t = threadIdx.x;

    for (int k = 0; k < 8; ++k) {
        const int c = (xcc + k) & 7;               // own class first, then steal
        const float wc = wsf[c];
        const size_t cbase = (size_t)c * N;
        float* pplane = partial + (size_t)c * EP;
        for (;;) {
            if (t == 0) s_chunk = atomicAdd(&ctr[c], 1);
            __syncthreads();
            const int chunk = s_chunk;
            if (chunk >= nchunk) { __syncthreads(); break; }
            const int e0 = chunk * CH;
            const int n = min(CH, E - e0);
            if (n == CH) {
                const int4* ps = (const int4*)(src + e0);
                const int4* pd = (const int4*)(dst + e0);
                #pragma unroll
                for (int i = 0; i < 4; ++i) {
                    ((int4*)s_src)[t + i * 256] = ps[t + i * 256];
                    ((int4*)s_dst)[t + i * 256] = pd[t + i * 256];
                }
            } else {
                for (int i = t; i < n; i += 256) {
                    s_src[i] = src[e0 + i];
                    s_dst[i] = dst[e0 + i];
                }
            }
            __syncthreads();
            const int g = t >> 3, j = t & 7;
            #pragma unroll 4
            for (int i = g; i < n; i += 32) {
                const int sn = s_src[i], dn = s_dst[i];
                const unsigned ua = slices[(cbase + sn) * 8 + j];
                const unsigned ub = slices[(cbase + dn) * 8 + j];
                float2 fa = __half22float2(*(const __half2*)&ua);
                float2 fb = __half22float2(*(const __half2*)&ub);
                const float d0 = fa.x - fb.x, d1 = fa.y - fb.y;
                float ss = d0 * d0 + d1 * d1;
                ss += __shfl_xor(ss, 1);
                ss += __shfl_xor(ss, 2);
                ss += __shfl_xor(ss, 4);
                if (j == 0) pplane[e0 + i] = sqrtf(ss) * wc;
            }
            __syncthreads();
        }
    }
}

__device__ __forceinline__ float edge_dist32(float4 a, float4 c, float wgt) {
    float dx = c.x - a.x, dy = c.y - a.y, dz = c.z - a.z, dw = c.w - a.w;
    float ss = dx * dx + dy * dy + dz * dz + dw * dw;
    ss += __shfl_xor(ss, 1);
    ss += __shfl_xor(ss, 2);
    float t = sqrtf(ss) * wgt;
    t += __shfl_xor(t, 4);
    t += __shfl_xor(t, 8);
    t += __shfl_xor(t, 16);
    return t;
}

// phase 2: sum partials -> dist; refine near-boundary edges with exact f32
__global__ __launch_bounds__(256) void expand_kernel(
    const float* __restrict__ h,
    const float* __restrict__ partial,
    const int* __restrict__ src,
    const int* __restrict__ dst,
    const float* __restrict__ ws,
    float* __restrict__ out,
    int E, long long EP) {
    __shared__ int s_src[XEB];
    __shared__ int s_dst[XEB];
    __shared__ float s_w[8];
    __shared__ float s_m[32];
    __shared__ float s_b;

    const int t = threadIdx.x;
    if (t < 8)  s_w[t] = ws[t];
    if (t < 32) s_m[t] = ws[8 + t];
    if (t == 0) s_b = ws[40];

    const long long base = (long long)blockIdx.x * XEB;
    if (base + XEB <= (long long)E) {
        ((int4*)s_src)[t] = ((const int4*)(src + base))[t];
        ((int4*)s_dst)[t] = ((const int4*)(dst + base))[t];
    } else {
        for (int i = t; i < XEB; i += 256) {
            long long e = base + i;
            s_src[i] = (e < (long long)E) ? src[e] : 0;
            s_dst[i] = (e < (long long)E) ? dst[e] : 0;
        }
    }
    __syncthreads();

    const int lane32 = t & 31;
    const int half32 = (t >> 5) & 1;
    const int group  = t >> 5;
    const float wgt  = s_w[lane32 >> 2];
    const float m_c  = s_m[lane32];
    const float bb   = s_b;

    for (int i = group * 128; i < group * 128 + 128; ++i) {
        const long long e = base + i;
        if (e >= (long long)E) break;
        float dist = 0.f;
        #pragma unroll
        for (int c = 0; c < 8; ++c) dist += partial[(size_t)c * EP + e];
        float margin = dist - m_c;
        const bool near = fabsf(margin) < THETA;
        unsigned long long mask = __ballot(near);
        unsigned gm = (unsigned)(mask >> (half32 ? 32 : 0));
        if (gm) {
            const int si = s_src[i], di = s_dst[i];
            float4 a = ((const float4*)(h + (size_t)si * 128))[lane32];
            float4 c = ((const float4*)(h + (size_t)di * 128))[lane32];
            float dd = edge_dist32(a, c, wgt);
            margin = dd - m_c;
        }
        __builtin_nontemporal_store(1.0f / (margin * margin + bb),
                                    out + (size_t)e * 32 + lane32);
    }
}

// fallback: pure-f32 direct (proven R1 path), used if ws too small
__global__ __launch_bounds__(256) void score_kernel_f32(
    const float* __restrict__ h,
    const int* __restrict__ src,
    const int* __restrict__ dst,
    const float* __restrict__ ws,
    float* __restrict__ out,
    int E) {
    __shared__ float s_w[8];
    __shared__ float s_m[32];
    __shared__ float s_b;
    const int t = threadIdx.x;
    if (t < 8)  s_w[t] = ws[t];
    if (t < 32) s_m[t] = ws[8 + t];
    if (t == 0) s_b = ws[40];
    __syncthreads();
    const int lane32 = t & 31;
    const int group  = t >> 5;
    const int gid    = blockIdx.x * 8 + group;
    const int stride = gridDim.x * 8;
    const float wgt  = s_w[lane32 >> 2];
    const float m_c  = s_m[lane32];
    const float bb   = s_b;
    for (int e = gid; e < E; e += stride) {
        const int si = src[e], di = dst[e];
        float4 a = ((const float4*)(h + (size_t)si * 128))[lane32];
        float4 c = ((const float4*)(h + (size_t)di * 128))[lane32];
        float tt = edge_dist32(a, c, wgt);
        float dm = tt - m_c;
        __builtin_nontemporal_store(1.0f / (dm * dm + bb),
                                    out + (size_t)e * 32 + lane32);
    }
}

extern "C" void kernel_launch(void* const* d_in, const int* in_sizes, int n_in,
                              void* d_out, int out_size, void* d_ws, size_t ws_size,
                              hipStream_t stream) {
    const float* h      = (const float*)d_in[0];
    const float* w      = (const float*)d_in[1];
    const float* r_dist = (const float*)d_in[2];
    const float* b      = (const float*)d_in[3];
    const int*   src    = (const int*)d_in[4];
    const int*   dst    = (const int*)d_in[5];
    float* out = (float*)d_out;
    float* ws  = (float*)d_ws;
    const int E = in_sizes[4];
    const int N = in_sizes[0] / 128;          // N*H*D / (8*16)

    const long long EP = ((long long)E + 255) & ~255LL;
    const size_t slice_off = 4096;
    const size_t slice_bytes = (size_t)8 * N * 32;
    const size_t part_off = slice_off + slice_bytes;
    const size_t need = part_off + (size_t)8 * EP * 4;

    if (ws_size >= need) {
        unsigned* slices = (unsigned*)((char*)d_ws + slice_off);
        float* partial   = (float*)((char*)d_ws + part_off);
        int* ctr         = (int*)((char*)d_ws + 256);
        const int nchunk = (E + CH - 1) / CH;
        const int cvt_blocks = (int)(((long long)N * 8 + 255) / 256);

        convert_kernel<<<cvt_blocks, 256, 0, stream>>>(h, w, r_dist, b, ws,
                                                       slices, ctr, N);
        phase1_kernel<<<2048, 256, 0, stream>>>(slices, src, dst, ws, partial,
                                                ctr, E, N, EP, nchunk);
        expand_kernel<<<(E + XEB - 1) / XEB, 256, 0, stream>>>(
            h, partial, src, dst, ws, out, E, EP);
    } else {
        param_kernel<<<1, 64, 0, stream>>>(w, r_dist, b, ws);
        score_kernel_f32<<<2048, 256, 0, stream>>>(h, src, dst, ws, out, E);
    }
}